// Round 7
// baseline (464.041 us; speedup 1.0000x reference)
//
#include <hip/hip_runtime.h>

#define N_NODES 100000
#define N_EDGES 1000000
#define N_GRAPHS 512
#define VOCAB 10000
#define DIM 64

#define NPB 64                                // nodes per bucket (dst>>6)
#define NB 1563                               // ceil(N_NODES/NPB)
#define EPB 2048                              // edges per hist/scatter block
#define SB 489                                // ceil(N_EDGES/EPB)
#define NELEMS (NB * SB)                      // 764,307 (bucket,block) counters
#define SCAN_B 1024
#define NSCAN ((NELEMS + SCAN_B - 1) / SCAN_B)  // 747

typedef unsigned short ushort_t;

// f32 -> bf16 round-to-nearest-even
static __device__ __forceinline__ ushort_t f2bf(float f) {
    unsigned u = __float_as_uint(f);
    unsigned r = 0x7FFFu + ((u >> 16) & 1u);
    return (ushort_t)((u + r) >> 16);
}
#define BFLO(u) __uint_as_float((u) << 16)
#define BFHI(u) __uint_as_float((u) & 0xFFFF0000u)

// ---------------------------------------------------------------------------
// Kernel 1: bf16 transformed tables Tb[m][v][j] = (embed @ W_m), m=0 root.
__global__ void build_tables(const float* __restrict__ embed,
                             const float* __restrict__ W_rel,
                             const float* __restrict__ W_root,
                             ushort_t* __restrict__ Tb) {
    int tid  = blockIdx.x * 256 + threadIdx.x;
    int l    = tid & 63;
    int wave = tid >> 6;              // 0..9999
    int sub  = l >> 4;                // row-within-wave 0..3
    int q    = l & 15;                // feature quad
    int row  = wave * 4 + sub;        // wave never crosses m (10000%4==0)
    int m    = row / VOCAB;
    int v    = row - m * VOCAB;
    const float* W = (m == 0) ? W_root : (W_rel + (size_t)(m - 1) * DIM * DIM);
    float4 e4  = *(const float4*)(embed + (size_t)v * DIM + q * 4);
    float4 acc = {0.f, 0.f, 0.f, 0.f};
#pragma unroll
    for (int kk = 0; kk < 16; ++kk) {
        int srcl = sub * 16 + kk;
        float ex = __shfl(e4.x, srcl, 64);
        float ey = __shfl(e4.y, srcl, 64);
        float ez = __shfl(e4.z, srcl, 64);
        float ew = __shfl(e4.w, srcl, 64);
        const float4 w0 = *(const float4*)(W + (4 * kk + 0) * DIM + q * 4);
        const float4 w1 = *(const float4*)(W + (4 * kk + 1) * DIM + q * 4);
        const float4 w2 = *(const float4*)(W + (4 * kk + 2) * DIM + q * 4);
        const float4 w3 = *(const float4*)(W + (4 * kk + 3) * DIM + q * 4);
        acc.x += ex * w0.x; acc.y += ex * w0.y; acc.z += ex * w0.z; acc.w += ex * w0.w;
        acc.x += ey * w1.x; acc.y += ey * w1.y; acc.z += ey * w1.z; acc.w += ey * w1.w;
        acc.x += ez * w2.x; acc.y += ez * w2.y; acc.z += ez * w2.z; acc.w += ez * w2.w;
        acc.x += ew * w3.x; acc.y += ew * w3.y; acc.z += ew * w3.z; acc.w += ew * w3.w;
    }
    ushort_t* p = Tb + (size_t)row * DIM + q * 4;
    p[0] = f2bf(acc.x); p[1] = f2bf(acc.y);
    p[2] = f2bf(acc.z); p[3] = f2bf(acc.w);
}

// ---------------------------------------------------------------------------
// Kernel 2: per-block bucket histogram (LDS atomics only).
__global__ __launch_bounds__(256)
void bucket_hist(const int* __restrict__ dst, int* __restrict__ bh) {
    __shared__ int h[NB];
    for (int i = threadIdx.x; i < NB; i += 256) h[i] = 0;
    __syncthreads();
    int base = blockIdx.x * EPB;
    int lim  = base + EPB; if (lim > N_EDGES) lim = N_EDGES;
    for (int e = base + threadIdx.x; e < lim; e += 256)
        atomicAdd(&h[dst[e] >> 6], 1);               // LDS atomic
    __syncthreads();
    for (int i = threadIdx.x; i < NB; i += 256)
        bh[i * SB + blockIdx.x] = h[i];              // bucket-major
}

// ---------------------------------------------------------------------------
// Kernel 3a: per-1024-block exclusive scan (shfl-based).
__global__ __launch_bounds__(SCAN_B)
void scan_block(const int* __restrict__ bh, int* __restrict__ obh,
                int* __restrict__ bsum) {
    __shared__ int wsum[16];
    int i  = blockIdx.x * SCAN_B + threadIdx.x;
    int l  = threadIdx.x & 63;
    int wv = threadIdx.x >> 6;
    int v  = (i < NELEMS) ? bh[i] : 0;
    int s  = v;
#pragma unroll
    for (int d = 1; d < 64; d <<= 1) {
        int t = __shfl_up(s, d, 64);
        if (l >= d) s += t;
    }
    if (l == 63) wsum[wv] = s;
    __syncthreads();
    if (wv == 0) {
        int wval = (l < 16) ? wsum[l] : 0;
        int ss = wval;
#pragma unroll
        for (int d = 1; d < 16; d <<= 1) {
            int t = __shfl_up(ss, d, 64);
            if (l >= d) ss += t;
        }
        if (l == 15) bsum[blockIdx.x] = ss;
        if (l < 16)  wsum[l] = ss - wval;
    }
    __syncthreads();
    if (i < NELEMS) obh[i] = s - v + wsum[wv];
}

// Kernel 3b: add global block base (lane-strided partial sums of bsum).
__global__ __launch_bounds__(SCAN_B)
void scan_add(int* __restrict__ obh, const int* __restrict__ bsum) {
    __shared__ int base_sh;
    int blk = blockIdx.x;
    if (threadIdx.x < 64) {
        int l = threadIdx.x;
        int t = 0;
        for (int i = l; i < blk; i += 64) t += bsum[i];
#pragma unroll
        for (int d = 32; d > 0; d >>= 1) t += __shfl_xor(t, d, 64);
        if (l == 0) base_sh = t;
    }
    __syncthreads();
    int i = blk * SCAN_B + threadIdx.x;
    if (i < NELEMS) obh[i] += base_sh;
}

// ---------------------------------------------------------------------------
// Kernel 4: bucket scatter. Local rank via returning LDS atomic; global
// position = obh[bucket*SB + block] + rank. Record = (x[src]<<8|dlow<<2|rel).
__global__ __launch_bounds__(256)
void bucket_scatter(const int* __restrict__ src,
                    const int* __restrict__ dst,
                    const int* __restrict__ etype,
                    const int* __restrict__ x,
                    const int* __restrict__ obh,
                    unsigned* __restrict__ rec) {
    __shared__ int baseh[NB];
    __shared__ int h[NB];
    for (int i = threadIdx.x; i < NB; i += 256) {
        baseh[i] = obh[i * SB + blockIdx.x];
        h[i] = 0;
    }
    __syncthreads();
    int base = blockIdx.x * EPB;
    int lim  = base + EPB; if (lim > N_EDGES) lim = N_EDGES;
    for (int e = base + threadIdx.x; e < lim; e += 256) {
        int d = dst[e];
        int b = d >> 6;
        int rk = atomicAdd(&h[b], 1);                // LDS returning atomic (fast)
        unsigned payload = ((unsigned)x[src[e]] << 8)
                         | ((unsigned)(d & 63) << 2)
                         | (unsigned)etype[e];
        rec[baseh[b] + rk] = payload;
    }
}

// ---------------------------------------------------------------------------
// Kernel 5: block-per-bucket aggregation with LDS accumulators.
// Pass 1: per-(node,rel) counts (LDS atomics). Pass 2: 32 edge slots x
// 8 lanes, each lane one uint4 (8 bf16) of the T row -> 8 ds_add_f32.
__global__ __launch_bounds__(256)
void aggregate_bucket(const int* __restrict__ x,
                      const int* __restrict__ obh,
                      const unsigned* __restrict__ rec,
                      const ushort_t* __restrict__ Tb,
                      const float* __restrict__ bias,
                      float* __restrict__ node_out) {
    __shared__ float accum[NPB * DIM];    // 16 KB
    __shared__ float inv_sh[NPB * 4];
    __shared__ int   cnt[NPB * 4];
    __shared__ int   x_sh[NPB];
    int b = blockIdx.x;
    int t = threadIdx.x;
    int s = obh[b * SB];
    int e = (b + 1 < NB) ? obh[(b + 1) * SB] : N_EDGES;
    int nodebase = b * NPB;

    for (int i = t; i < NPB * DIM; i += 256) accum[i] = 0.f;
    for (int i = t; i < NPB * 4; i += 256) cnt[i] = 0;
    if (t < NPB && nodebase + t < N_NODES) x_sh[t] = x[nodebase + t];
    __syncthreads();

    // pass 1: per-(node,rel) counts
    for (int i = s + t; i < e; i += 256) {
        unsigned p = rec[i];
        atomicAdd(&cnt[((p >> 2) & 63) * 4 + (p & 3)], 1);
    }
    __syncthreads();
    for (int i = t; i < NPB * 4; i += 256)
        inv_sh[i] = 1.f / fmaxf((float)cnt[i], 1.f);
    __syncthreads();

    // pass 2: scaled accumulation
    int slot = t >> 3;                    // 0..31
    int sl   = t & 7;                     // 8 bf16 sub-row per lane
    for (int i = s + slot; i < e; i += 32) {
        unsigned p = rec[i];              // same addr for 8 lanes -> L1 broadcast
        int r = (int)(p & 3u);
        int n = (int)((p >> 2) & 63u);
        int v = (int)(p >> 8);
        float iv = inv_sh[(n << 2) + r];
        const uint4* rowp = (const uint4*)(Tb + ((size_t)(1 + r) * VOCAB + v) * DIM);
        uint4 tv = rowp[sl];
        float* ac = accum + n * DIM + sl * 8;
        atomicAdd(ac + 0, BFLO(tv.x) * iv);
        atomicAdd(ac + 1, BFHI(tv.x) * iv);
        atomicAdd(ac + 2, BFLO(tv.y) * iv);
        atomicAdd(ac + 3, BFHI(tv.y) * iv);
        atomicAdd(ac + 4, BFLO(tv.z) * iv);
        atomicAdd(ac + 5, BFHI(tv.z) * iv);
        atomicAdd(ac + 6, BFLO(tv.w) * iv);
        atomicAdd(ac + 7, BFHI(tv.w) * iv);
    }
    __syncthreads();

    // finalize: root + bias + accum, ReLU, coalesced write
    for (int i = t; i < NPB * DIM; i += 256) {
        int n = i >> 6, f = i & 63;
        int node = nodebase + n;
        if (node < N_NODES) {
            float root = __uint_as_float((unsigned)Tb[(size_t)x_sh[n] * DIM + f] << 16);
            float o = root + bias[f] + accum[i];
            node_out[(size_t)node * DIM + f] = fmaxf(o, 0.f);
        }
    }
}

// ---------------------------------------------------------------------------
// Kernel 6: per-graph mean pool + 64->2 linear. batch is SORTED. 8 waves/blk.
__device__ __forceinline__ int lbound(const int* __restrict__ b, int val) {
    int lo = 0, hi = N_NODES;
    while (lo < hi) {
        int mid = (lo + hi) >> 1;
        if (b[mid] < val) lo = mid + 1; else hi = mid;
    }
    return lo;
}

__global__ __launch_bounds__(512)
void pool_linear(const int* __restrict__ batch,
                 const float* __restrict__ node_out,
                 const float* __restrict__ lin_W,
                 const float* __restrict__ lin_b,
                 float* __restrict__ out) {
    __shared__ float sh[512];
    int g = blockIdx.x;
    int lane = threadIdx.x & 63;
    int w = threadIdx.x >> 6;      // 0..7
    int s = lbound(batch, g);
    int e = lbound(batch, g + 1);
    float acc = 0.f;
    for (int i = s + w; i < e; i += 8)
        acc += node_out[(size_t)i * DIM + lane];
    sh[threadIdx.x] = acc;
    __syncthreads();
    if (w == 0) {
        float tot = 0.f;
#pragma unroll
        for (int k = 0; k < 8; ++k) tot += sh[k * 64 + lane];
        float cnt = (float)(e - s);
        float mean = (e > s) ? tot / cnt : 0.f;
        float p0 = mean * lin_W[lane * 2 + 0];
        float p1 = mean * lin_W[lane * 2 + 1];
#pragma unroll
        for (int off2 = 32; off2 > 0; off2 >>= 1) {
            p0 += __shfl_down(p0, off2, 64);
            p1 += __shfl_down(p1, off2, 64);
        }
        if (lane == 0) {
            out[g * 2 + 0] = p0 + lin_b[0];
            out[g * 2 + 1] = p1 + lin_b[1];
        }
    }
}

// ---------------------------------------------------------------------------
extern "C" void kernel_launch(void* const* d_in, const int* in_sizes, int n_in,
                              void* d_out, int out_size, void* d_ws, size_t ws_size,
                              hipStream_t stream) {
    const int*   x      = (const int*)d_in[0];
    const int*   eidx   = (const int*)d_in[1];   // [2, E]
    const int*   etype  = (const int*)d_in[2];
    const int*   batch  = (const int*)d_in[3];
    const float* embed  = (const float*)d_in[4];
    const float* W_rel  = (const float*)d_in[5];
    const float* W_root = (const float*)d_in[6];
    const float* bias   = (const float*)d_in[7];
    const float* lin_W  = (const float*)d_in[8];
    const float* lin_b  = (const float*)d_in[9];
    float* out = (float*)d_out;

    const int* src = eidx;
    const int* dst = eidx + N_EDGES;

    // Workspace layout (bytes). No memset needed — every buffer fully written.
    //   rec      : 1M*4           =  4,000,000
    //   obh      : NELEMS*4       =  3,057,228   (at  4,000,000)
    //   bsum     : NSCAN*4        =      2,988   (at  7,057,280)
    //   Tb       : 4*VOCAB*64*2   =  5,120,000   (at  7,060,352, 16B-aligned)
    //   node_out : N*64*4         = 25,600,000   (at 12,180,480)
    //   bh aliases node_out base (dead before aggregate writes node_out)
    char* ws = (char*)d_ws;
    unsigned* rec   = (unsigned*)(ws);
    int* obh        = (int*)(ws + 4000000);
    int* bsum       = (int*)(ws + 7057280);
    ushort_t* Tb    = (ushort_t*)(ws + 7060352);
    float* node_out = (float*)(ws + 12180480);
    int* bh         = (int*)(ws + 12180480);     // alias: dead after scan_block

    // 1. per-block bucket histogram (LDS atomics)
    bucket_hist<<<SB, 256, 0, stream>>>(dst, bh);

    // 2. bf16 transformed tables (independent; needed by aggregate)
    build_tables<<<(4 * VOCAB) / 16, 256, 0, stream>>>(embed, W_rel, W_root, Tb);

    // 3. exclusive scan of (bucket,block) counts
    scan_block<<<NSCAN, SCAN_B, 0, stream>>>(bh, obh, bsum);
    scan_add<<<NSCAN, SCAN_B, 0, stream>>>(obh, bsum);

    // 4. bucket scatter (LDS ranks, no device atomics)
    bucket_scatter<<<SB, 256, 0, stream>>>(src, dst, etype, x, obh, rec);

    // 5. block-per-bucket aggregation (LDS accumulators)
    aggregate_bucket<<<NB, 256, 0, stream>>>(x, obh, rec, Tb, bias, node_out);

    // 6. per-graph pool + linear
    pool_linear<<<N_GRAPHS, 512, 0, stream>>>(batch, node_out, lin_W, lin_b, out);
}

// Round 8
// 132.077 us; speedup vs baseline: 3.5134x; 3.5134x over previous
//
#include <hip/hip_runtime.h>

#define N_NODES 100000
#define N_EDGES 1000000
#define N_GRAPHS 512
#define VOCAB 10000
#define DIM 64

#define NPB 64                                // nodes per bucket (dst>>6)
#define NB 1563                               // ceil(N_NODES/NPB)
#define EPB 2048                              // edges per hist/scatter block
#define SB 489                                // ceil(N_EDGES/EPB)
#define NELEMS (NB * SB)                      // 764,307 (bucket,block) counters
#define SCAN_B 1024
#define NSCAN ((NELEMS + SCAN_B - 1) / SCAN_B)  // 747

typedef unsigned short ushort_t;

// f32 -> bf16 round-to-nearest-even
static __device__ __forceinline__ ushort_t f2bf(float f) {
    unsigned u = __float_as_uint(f);
    unsigned r = 0x7FFFu + ((u >> 16) & 1u);
    return (ushort_t)((u + r) >> 16);
}
#define BFLO(u) __uint_as_float((u) << 16)
#define BFHI(u) __uint_as_float((u) & 0xFFFF0000u)

// ---------------------------------------------------------------------------
// Kernel 1: bf16 transformed tables Tb[m][v][j] = (embed @ W_m), m=0 root.
__global__ void build_tables(const float* __restrict__ embed,
                             const float* __restrict__ W_rel,
                             const float* __restrict__ W_root,
                             ushort_t* __restrict__ Tb) {
    int tid  = blockIdx.x * 256 + threadIdx.x;
    int l    = tid & 63;
    int wave = tid >> 6;              // 0..9999
    int sub  = l >> 4;                // row-within-wave 0..3
    int q    = l & 15;                // feature quad
    int row  = wave * 4 + sub;        // wave never crosses m (10000%4==0)
    int m    = row / VOCAB;
    int v    = row - m * VOCAB;
    const float* W = (m == 0) ? W_root : (W_rel + (size_t)(m - 1) * DIM * DIM);
    float4 e4  = *(const float4*)(embed + (size_t)v * DIM + q * 4);
    float4 acc = {0.f, 0.f, 0.f, 0.f};
#pragma unroll
    for (int kk = 0; kk < 16; ++kk) {
        int srcl = sub * 16 + kk;
        float ex = __shfl(e4.x, srcl, 64);
        float ey = __shfl(e4.y, srcl, 64);
        float ez = __shfl(e4.z, srcl, 64);
        float ew = __shfl(e4.w, srcl, 64);
        const float4 w0 = *(const float4*)(W + (4 * kk + 0) * DIM + q * 4);
        const float4 w1 = *(const float4*)(W + (4 * kk + 1) * DIM + q * 4);
        const float4 w2 = *(const float4*)(W + (4 * kk + 2) * DIM + q * 4);
        const float4 w3 = *(const float4*)(W + (4 * kk + 3) * DIM + q * 4);
        acc.x += ex * w0.x; acc.y += ex * w0.y; acc.z += ex * w0.z; acc.w += ex * w0.w;
        acc.x += ey * w1.x; acc.y += ey * w1.y; acc.z += ey * w1.z; acc.w += ey * w1.w;
        acc.x += ez * w2.x; acc.y += ez * w2.y; acc.z += ez * w2.z; acc.w += ez * w2.w;
        acc.x += ew * w3.x; acc.y += ew * w3.y; acc.z += ew * w3.z; acc.w += ew * w3.w;
    }
    ushort_t* p = Tb + (size_t)row * DIM + q * 4;
    p[0] = f2bf(acc.x); p[1] = f2bf(acc.y);
    p[2] = f2bf(acc.z); p[3] = f2bf(acc.w);
}

// ---------------------------------------------------------------------------
// Kernel 2: per-block bucket histogram (LDS int atomics only).
__global__ __launch_bounds__(256)
void bucket_hist(const int* __restrict__ dst, int* __restrict__ bh) {
    __shared__ int h[NB];
    for (int i = threadIdx.x; i < NB; i += 256) h[i] = 0;
    __syncthreads();
    int base = blockIdx.x * EPB;
    int lim  = base + EPB; if (lim > N_EDGES) lim = N_EDGES;
    for (int e = base + threadIdx.x; e < lim; e += 256)
        atomicAdd(&h[dst[e] >> 6], 1);               // LDS atomic
    __syncthreads();
    for (int i = threadIdx.x; i < NB; i += 256)
        bh[i * SB + blockIdx.x] = h[i];              // bucket-major
}

// ---------------------------------------------------------------------------
// Kernel 3a: per-1024-block exclusive scan (shfl-based).
__global__ __launch_bounds__(SCAN_B)
void scan_block(const int* __restrict__ bh, int* __restrict__ obh,
                int* __restrict__ bsum) {
    __shared__ int wsum[16];
    int i  = blockIdx.x * SCAN_B + threadIdx.x;
    int l  = threadIdx.x & 63;
    int wv = threadIdx.x >> 6;
    int v  = (i < NELEMS) ? bh[i] : 0;
    int s  = v;
#pragma unroll
    for (int d = 1; d < 64; d <<= 1) {
        int t = __shfl_up(s, d, 64);
        if (l >= d) s += t;
    }
    if (l == 63) wsum[wv] = s;
    __syncthreads();
    if (wv == 0) {
        int wval = (l < 16) ? wsum[l] : 0;
        int ss = wval;
#pragma unroll
        for (int d = 1; d < 16; d <<= 1) {
            int t = __shfl_up(ss, d, 64);
            if (l >= d) ss += t;
        }
        if (l == 15) bsum[blockIdx.x] = ss;
        if (l < 16)  wsum[l] = ss - wval;
    }
    __syncthreads();
    if (i < NELEMS) obh[i] = s - v + wsum[wv];
}

// Kernel 3b: add global block base (lane-strided partial sums of bsum).
__global__ __launch_bounds__(SCAN_B)
void scan_add(int* __restrict__ obh, const int* __restrict__ bsum) {
    __shared__ int base_sh;
    int blk = blockIdx.x;
    if (threadIdx.x < 64) {
        int l = threadIdx.x;
        int t = 0;
        for (int i = l; i < blk; i += 64) t += bsum[i];
#pragma unroll
        for (int d = 32; d > 0; d >>= 1) t += __shfl_xor(t, d, 64);
        if (l == 0) base_sh = t;
    }
    __syncthreads();
    int i = blk * SCAN_B + threadIdx.x;
    if (i < NELEMS) obh[i] += base_sh;
}

// ---------------------------------------------------------------------------
// Kernel 4: bucket scatter. Local rank via returning LDS atomic; global
// position = obh[bucket*SB + block] + rank. Record = (x[src]<<8|dlow<<2|rel).
__global__ __launch_bounds__(256)
void bucket_scatter(const int* __restrict__ src,
                    const int* __restrict__ dst,
                    const int* __restrict__ etype,
                    const int* __restrict__ x,
                    const int* __restrict__ obh,
                    unsigned* __restrict__ rec) {
    __shared__ int baseh[NB];
    __shared__ int h[NB];
    for (int i = threadIdx.x; i < NB; i += 256) {
        baseh[i] = obh[i * SB + blockIdx.x];
        h[i] = 0;
    }
    __syncthreads();
    int base = blockIdx.x * EPB;
    int lim  = base + EPB; if (lim > N_EDGES) lim = N_EDGES;
    for (int e = base + threadIdx.x; e < lim; e += 256) {
        int d = dst[e];
        int b = d >> 6;
        int rk = atomicAdd(&h[b], 1);                // LDS returning atomic (fast)
        unsigned payload = ((unsigned)x[src[e]] << 8)
                         | ((unsigned)(d & 63) << 2)
                         | (unsigned)etype[e];
        rec[baseh[b] + rk] = payload;
    }
}

// ---------------------------------------------------------------------------
// Kernel 5: per-bucket node sort. Converts bucket-grouped records into
// node-sorted elist + per-node off[]. Only LDS int atomics.
__global__ __launch_bounds__(256)
void node_sort(const unsigned* __restrict__ rec,
               const int* __restrict__ obh,
               ushort_t* __restrict__ elist,
               int* __restrict__ off) {
    __shared__ int cnt[NPB];
    __shared__ int cur[NPB];
    int b = blockIdx.x, t = threadIdx.x;
    int s = obh[b * SB];
    int e = (b + 1 < NB) ? obh[(b + 1) * SB] : N_EDGES;
    if (t < NPB) cnt[t] = 0;
    __syncthreads();
    // pass 1: per-node counts
    for (int i = s + t; i < e; i += 256)
        atomicAdd(&cnt[(rec[i] >> 2) & 63], 1);
    __syncthreads();
    // wave 0: 64-lane exclusive scan; publish off[] and cursors
    if (t < 64) {
        int v = cnt[t];
        int sc = v;
#pragma unroll
        for (int d = 1; d < 64; d <<= 1) {
            int tt = __shfl_up(sc, d, 64);
            if (t >= d) sc += tt;
        }
        int excl = sc - v;
        cur[t] = excl;
        int node = b * NPB + t;
        if (node < N_NODES) off[node] = s + excl;
    }
    __syncthreads();
    // pass 2: place payloads in node order within the bucket window
    for (int i = s + t; i < e; i += 256) {
        unsigned p = rec[i];
        int n = (int)((p >> 2) & 63u);
        int rk = atomicAdd(&cur[n], 1);
        elist[s + rk] = (ushort_t)(((p >> 8) << 2) | (p & 3u));
    }
    if (b == 0 && t == 0) off[N_NODES] = N_EDGES;
}

// ---------------------------------------------------------------------------
// Kernel 6: per-dst aggregation from bf16 tables (round-6 version, proven).
// lane = (g<<3)|q : g = edge-slot group (8 slots/iter), q = feature octet.
__global__ void aggregate(const int* __restrict__ x,
                          const int* __restrict__ off,
                          const ushort_t* __restrict__ elist,
                          const ushort_t* __restrict__ Tb,
                          const float* __restrict__ bias,
                          float* __restrict__ node_out) {
    int tid = blockIdx.x * 256 + threadIdx.x;
    int w = tid >> 6;                  // dst node id
    if (w >= N_NODES) return;
    int l = tid & 63;
    int g = l >> 3;                    // edge-slot group 0..7
    int q = l & 7;                     // feature octet 0..7
    int beg = off[w], end = off[w + 1];

    // per-relation counts: ballots over each 64-edge chunk
    int c0 = 0, c1 = 0, c2 = 0;
    for (int cb = beg; cb < end; cb += 64) {
        int idx = cb + l;
        unsigned pl = (idx < end) ? (unsigned)elist[idx] : 0xFFFFu;  // r=3 sentinel
        int r = (int)(pl & 3u);
        c0 += __popcll(__ballot(r == 0));
        c1 += __popcll(__ballot(r == 1));
        c2 += __popcll(__ballot(r == 2));
    }
    float inv0 = 1.f / fmaxf((float)c0, 1.f);
    float inv1 = 1.f / fmaxf((float)c1, 1.f);
    float inv2 = 1.f / fmaxf((float)c2, 1.f);

    float a0 = 0.f, a1 = 0.f, a2 = 0.f, a3 = 0.f,
          a4 = 0.f, a5 = 0.f, a6 = 0.f, a7 = 0.f;
    for (int cb = beg; cb < end; cb += 64) {
        int idx = cb + l;
        unsigned pl = (idx < end) ? (unsigned)elist[idx] : 0xFFFFu;  // L1-hot reload
        int rem = end - cb; if (rem > 64) rem = 64;
#pragma unroll
        for (int k = 0; k < 8; ++k) {
            if (k * 8 >= rem) break;                     // wave-uniform exit
            unsigned p = (unsigned)__shfl((int)pl, k * 8 + g, 64);
            bool valid = (p != 0xFFFFu);
            int r = valid ? (int)(p & 3u) : 0;
            int v = valid ? (int)(p >> 2) : 0;
            float iv = (r == 0) ? inv0 : ((r == 1) ? inv1 : inv2);
            iv = valid ? iv : 0.f;
            const uint4 t = *(const uint4*)(Tb + ((size_t)(1 + r) * VOCAB + v) * DIM + q * 8);
            a0 += BFLO(t.x) * iv; a1 += BFHI(t.x) * iv;
            a2 += BFLO(t.y) * iv; a3 += BFHI(t.y) * iv;
            a4 += BFLO(t.z) * iv; a5 += BFHI(t.z) * iv;
            a6 += BFLO(t.w) * iv; a7 += BFHI(t.w) * iv;
        }
    }
    // combine the 8 edge-slot groups (lanes with same q)
    a0 += __shfl_xor(a0, 8, 64); a0 += __shfl_xor(a0, 16, 64); a0 += __shfl_xor(a0, 32, 64);
    a1 += __shfl_xor(a1, 8, 64); a1 += __shfl_xor(a1, 16, 64); a1 += __shfl_xor(a1, 32, 64);
    a2 += __shfl_xor(a2, 8, 64); a2 += __shfl_xor(a2, 16, 64); a2 += __shfl_xor(a2, 32, 64);
    a3 += __shfl_xor(a3, 8, 64); a3 += __shfl_xor(a3, 16, 64); a3 += __shfl_xor(a3, 32, 64);
    a4 += __shfl_xor(a4, 8, 64); a4 += __shfl_xor(a4, 16, 64); a4 += __shfl_xor(a4, 32, 64);
    a5 += __shfl_xor(a5, 8, 64); a5 += __shfl_xor(a5, 16, 64); a5 += __shfl_xor(a5, 32, 64);
    a6 += __shfl_xor(a6, 8, 64); a6 += __shfl_xor(a6, 16, 64); a6 += __shfl_xor(a6, 32, 64);
    a7 += __shfl_xor(a7, 8, 64); a7 += __shfl_xor(a7, 16, 64); a7 += __shfl_xor(a7, 32, 64);

    if (g == 0) {                      // lanes 0..7 write the 64-float row
        const uint4 rt = *(const uint4*)(Tb + (size_t)x[w] * DIM + q * 8);
        const float4 b0 = *(const float4*)(bias + q * 8);
        const float4 b1 = *(const float4*)(bias + q * 8 + 4);
        float4 o0, o1;
        o0.x = fmaxf(BFLO(rt.x) + b0.x + a0, 0.f);
        o0.y = fmaxf(BFHI(rt.x) + b0.y + a1, 0.f);
        o0.z = fmaxf(BFLO(rt.y) + b0.z + a2, 0.f);
        o0.w = fmaxf(BFHI(rt.y) + b0.w + a3, 0.f);
        o1.x = fmaxf(BFLO(rt.z) + b1.x + a4, 0.f);
        o1.y = fmaxf(BFHI(rt.z) + b1.y + a5, 0.f);
        o1.z = fmaxf(BFLO(rt.w) + b1.z + a6, 0.f);
        o1.w = fmaxf(BFHI(rt.w) + b1.w + a7, 0.f);
        float* dstp = node_out + (size_t)w * DIM + q * 8;
        *(float4*)(dstp)     = o0;
        *(float4*)(dstp + 4) = o1;
    }
}

// ---------------------------------------------------------------------------
// Kernel 7: per-graph mean pool + 64->2 linear. batch is SORTED. 8 waves/blk.
__device__ __forceinline__ int lbound(const int* __restrict__ b, int val) {
    int lo = 0, hi = N_NODES;
    while (lo < hi) {
        int mid = (lo + hi) >> 1;
        if (b[mid] < val) lo = mid + 1; else hi = mid;
    }
    return lo;
}

__global__ __launch_bounds__(512)
void pool_linear(const int* __restrict__ batch,
                 const float* __restrict__ node_out,
                 const float* __restrict__ lin_W,
                 const float* __restrict__ lin_b,
                 float* __restrict__ out) {
    __shared__ float sh[512];
    int g = blockIdx.x;
    int lane = threadIdx.x & 63;
    int w = threadIdx.x >> 6;      // 0..7
    int s = lbound(batch, g);
    int e = lbound(batch, g + 1);
    float acc = 0.f;
    for (int i = s + w; i < e; i += 8)
        acc += node_out[(size_t)i * DIM + lane];
    sh[threadIdx.x] = acc;
    __syncthreads();
    if (w == 0) {
        float tot = 0.f;
#pragma unroll
        for (int k = 0; k < 8; ++k) tot += sh[k * 64 + lane];
        float cnt = (float)(e - s);
        float mean = (e > s) ? tot / cnt : 0.f;
        float p0 = mean * lin_W[lane * 2 + 0];
        float p1 = mean * lin_W[lane * 2 + 1];
#pragma unroll
        for (int off2 = 32; off2 > 0; off2 >>= 1) {
            p0 += __shfl_down(p0, off2, 64);
            p1 += __shfl_down(p1, off2, 64);
        }
        if (lane == 0) {
            out[g * 2 + 0] = p0 + lin_b[0];
            out[g * 2 + 1] = p1 + lin_b[1];
        }
    }
}

// ---------------------------------------------------------------------------
extern "C" void kernel_launch(void* const* d_in, const int* in_sizes, int n_in,
                              void* d_out, int out_size, void* d_ws, size_t ws_size,
                              hipStream_t stream) {
    const int*   x      = (const int*)d_in[0];
    const int*   eidx   = (const int*)d_in[1];   // [2, E]
    const int*   etype  = (const int*)d_in[2];
    const int*   batch  = (const int*)d_in[3];
    const float* embed  = (const float*)d_in[4];
    const float* W_rel  = (const float*)d_in[5];
    const float* W_root = (const float*)d_in[6];
    const float* bias   = (const float*)d_in[7];
    const float* lin_W  = (const float*)d_in[8];
    const float* lin_b  = (const float*)d_in[9];
    float* out = (float*)d_out;

    const int* src = eidx;
    const int* dst = eidx + N_EDGES;

    // Workspace layout (bytes). No memsets — every buffer fully written
    // before read. Transient CSR-build buffers alias the node_out region
    // (node_out is written only by aggregate, after they are dead).
    //   Tb       : 4*VOCAB*64*2  =  5,120,000   at          0
    //   elist    : 1M*2          =  2,000,000   at  5,120,000
    //   off      : (N+1)*4       =    400,004   at  7,120,000
    //   node_out : N*64*4        = 25,600,000   at  7,520,064
    //     rec    : 1M*4          =  4,000,000   at  7,520,064 (alias)
    //     obh    : NELEMS*4      =  3,057,228   at 11,520,064 (alias)
    //     bsum   : NSCAN*4       =      2,988   at 14,577,296 (alias)
    //     bh     : NELEMS*4      =  3,057,228   at 14,580,288 (alias)
    //   total 33.12 MB
    char* ws = (char*)d_ws;
    ushort_t* Tb    = (ushort_t*)(ws);
    ushort_t* elist = (ushort_t*)(ws + 5120000);
    int* off        = (int*)(ws + 7120000);
    float* node_out = (float*)(ws + 7520064);
    unsigned* rec   = (unsigned*)(ws + 7520064);
    int* obh        = (int*)(ws + 11520064);
    int* bsum       = (int*)(ws + 14577296);
    int* bh         = (int*)(ws + 14580288);

    // 1. per-block bucket histogram (LDS atomics)
    bucket_hist<<<SB, 256, 0, stream>>>(dst, bh);

    // 2. bf16 transformed tables (independent; needed by aggregate)
    build_tables<<<(4 * VOCAB) / 16, 256, 0, stream>>>(embed, W_rel, W_root, Tb);

    // 3. exclusive scan of (bucket,block) counts
    scan_block<<<NSCAN, SCAN_B, 0, stream>>>(bh, obh, bsum);
    scan_add<<<NSCAN, SCAN_B, 0, stream>>>(obh, bsum);

    // 4. bucket scatter (LDS ranks, no device atomics)
    bucket_scatter<<<SB, 256, 0, stream>>>(src, dst, etype, x, obh, rec);

    // 5. per-bucket node sort -> node-sorted elist + off[]
    node_sort<<<NB, 256, 0, stream>>>(rec, obh, elist, off);

    // 6. per-node aggregation (no atomics, bf16 tables)
    aggregate<<<(N_NODES * 64) / 256, 256, 0, stream>>>(x, off, elist, Tb, bias, node_out);

    // 7. per-graph pool + linear
    pool_linear<<<N_GRAPHS, 512, 0, stream>>>(batch, node_out, lin_W, lin_b, out);
}

// Round 9
// 103.896 us; speedup vs baseline: 4.4664x; 1.2712x over previous
//
#include <hip/hip_runtime.h>

#define N_NODES 100000
#define N_EDGES 1000000
#define N_GRAPHS 512
#define VOCAB 10000
#define DIM 64

#define NPB 64                                // nodes per bucket (dst>>6)
#define NB 1563                               // ceil(N_NODES/NPB)
#define EPB 4096                              // edges per hist/scatter block
#define SB 245                                // ceil(N_EDGES/EPB)
#define NELEMS (NB * SB)                      // 382,935 (bucket,block) counters
#define SCAN_B 1024
#define NSCAN ((NELEMS + SCAN_B - 1) / SCAN_B)  // 374
#define CAP 1152                              // LDS sorted-list capacity (mean 640, sigma 25)

typedef unsigned short ushort_t;

// f32 -> bf16 round-to-nearest-even
static __device__ __forceinline__ ushort_t f2bf(float f) {
    unsigned u = __float_as_uint(f);
    unsigned r = 0x7FFFu + ((u >> 16) & 1u);
    return (ushort_t)((u + r) >> 16);
}
#define BFLO(u) __uint_as_float((u) << 16)
#define BFHI(u) __uint_as_float((u) & 0xFFFF0000u)

// ---------------------------------------------------------------------------
// Kernel 1: bf16 transformed tables Tb[m][v][j] = (embed @ W_m), m=0 root.
__global__ void build_tables(const float* __restrict__ embed,
                             const float* __restrict__ W_rel,
                             const float* __restrict__ W_root,
                             ushort_t* __restrict__ Tb) {
    int tid  = blockIdx.x * 256 + threadIdx.x;
    int l    = tid & 63;
    int wave = tid >> 6;              // 0..9999
    int sub  = l >> 4;                // row-within-wave 0..3
    int q    = l & 15;                // feature quad
    int row  = wave * 4 + sub;        // wave never crosses m (10000%4==0)
    int m    = row / VOCAB;
    int v    = row - m * VOCAB;
    const float* W = (m == 0) ? W_root : (W_rel + (size_t)(m - 1) * DIM * DIM);
    float4 e4  = *(const float4*)(embed + (size_t)v * DIM + q * 4);
    float4 acc = {0.f, 0.f, 0.f, 0.f};
#pragma unroll
    for (int kk = 0; kk < 16; ++kk) {
        int srcl = sub * 16 + kk;
        float ex = __shfl(e4.x, srcl, 64);
        float ey = __shfl(e4.y, srcl, 64);
        float ez = __shfl(e4.z, srcl, 64);
        float ew = __shfl(e4.w, srcl, 64);
        const float4 w0 = *(const float4*)(W + (4 * kk + 0) * DIM + q * 4);
        const float4 w1 = *(const float4*)(W + (4 * kk + 1) * DIM + q * 4);
        const float4 w2 = *(const float4*)(W + (4 * kk + 2) * DIM + q * 4);
        const float4 w3 = *(const float4*)(W + (4 * kk + 3) * DIM + q * 4);
        acc.x += ex * w0.x; acc.y += ex * w0.y; acc.z += ex * w0.z; acc.w += ex * w0.w;
        acc.x += ey * w1.x; acc.y += ey * w1.y; acc.z += ey * w1.z; acc.w += ey * w1.w;
        acc.x += ez * w2.x; acc.y += ez * w2.y; acc.z += ez * w2.z; acc.w += ez * w2.w;
        acc.x += ew * w3.x; acc.y += ew * w3.y; acc.z += ew * w3.z; acc.w += ew * w3.w;
    }
    ushort_t* p = Tb + (size_t)row * DIM + q * 4;
    p[0] = f2bf(acc.x); p[1] = f2bf(acc.y);
    p[2] = f2bf(acc.z); p[3] = f2bf(acc.w);
}

// ---------------------------------------------------------------------------
// Kernel 2: per-block bucket histogram (LDS int atomics only).
__global__ __launch_bounds__(256)
void bucket_hist(const int* __restrict__ dst, int* __restrict__ bh) {
    __shared__ int h[NB];
    for (int i = threadIdx.x; i < NB; i += 256) h[i] = 0;
    __syncthreads();
    int base = blockIdx.x * EPB;
    int lim  = base + EPB; if (lim > N_EDGES) lim = N_EDGES;
    for (int e = base + threadIdx.x; e < lim; e += 256)
        atomicAdd(&h[dst[e] >> 6], 1);               // LDS atomic
    __syncthreads();
    for (int i = threadIdx.x; i < NB; i += 256)
        bh[i * SB + blockIdx.x] = h[i];              // bucket-major
}

// ---------------------------------------------------------------------------
// Kernel 3a: per-1024-block exclusive scan (shfl-based).
__global__ __launch_bounds__(SCAN_B)
void scan_block(const int* __restrict__ bh, int* __restrict__ obh,
                int* __restrict__ bsum) {
    __shared__ int wsum[16];
    int i  = blockIdx.x * SCAN_B + threadIdx.x;
    int l  = threadIdx.x & 63;
    int wv = threadIdx.x >> 6;
    int v  = (i < NELEMS) ? bh[i] : 0;
    int s  = v;
#pragma unroll
    for (int d = 1; d < 64; d <<= 1) {
        int t = __shfl_up(s, d, 64);
        if (l >= d) s += t;
    }
    if (l == 63) wsum[wv] = s;
    __syncthreads();
    if (wv == 0) {
        int wval = (l < 16) ? wsum[l] : 0;
        int ss = wval;
#pragma unroll
        for (int d = 1; d < 16; d <<= 1) {
            int t = __shfl_up(ss, d, 64);
            if (l >= d) ss += t;
        }
        if (l == 15) bsum[blockIdx.x] = ss;
        if (l < 16)  wsum[l] = ss - wval;
    }
    __syncthreads();
    if (i < NELEMS) obh[i] = s - v + wsum[wv];
}

// Kernel 3b: add global block base (lane-strided partial sums of bsum).
__global__ __launch_bounds__(SCAN_B)
void scan_add(int* __restrict__ obh, const int* __restrict__ bsum) {
    __shared__ int base_sh;
    int blk = blockIdx.x;
    if (threadIdx.x < 64) {
        int l = threadIdx.x;
        int t = 0;
        for (int i = l; i < blk; i += 64) t += bsum[i];
#pragma unroll
        for (int d = 32; d > 0; d >>= 1) t += __shfl_xor(t, d, 64);
        if (l == 0) base_sh = t;
    }
    __syncthreads();
    int i = blk * SCAN_B + threadIdx.x;
    if (i < NELEMS) obh[i] += base_sh;
}

// ---------------------------------------------------------------------------
// Kernel 4: bucket scatter. Local rank via returning LDS atomic; global
// position = obh[bucket*SB + block] + rank. Record = (x[src]<<8|nlow<<2|rel).
__global__ __launch_bounds__(256)
void bucket_scatter(const int* __restrict__ src,
                    const int* __restrict__ dst,
                    const int* __restrict__ etype,
                    const int* __restrict__ x,
                    const int* __restrict__ obh,
                    unsigned* __restrict__ rec) {
    __shared__ int baseh[NB];
    __shared__ int h[NB];
    for (int i = threadIdx.x; i < NB; i += 256) {
        baseh[i] = obh[i * SB + blockIdx.x];
        h[i] = 0;
    }
    __syncthreads();
    int base = blockIdx.x * EPB;
    int lim  = base + EPB; if (lim > N_EDGES) lim = N_EDGES;
    for (int e = base + threadIdx.x; e < lim; e += 256) {
        int d = dst[e];
        int b = d >> 6;
        int rk = atomicAdd(&h[b], 1);                // LDS returning atomic (fast)
        unsigned payload = ((unsigned)x[src[e]] << 8)
                         | ((unsigned)(d & 63) << 2)
                         | (unsigned)etype[e];
        rec[baseh[b] + rk] = payload;
    }
}

// ---------------------------------------------------------------------------
// Kernel 5 (fused node_sort + aggregate): block per bucket.
// Phase 1: count per (node,rel) key (256 LDS counters) -> 256-wide scan ->
//          place v into LDS sorted list via returning LDS cursors.
// Phase 2: 32 groups x 8 lanes; group owns 2 nodes; per relation segment
//          gather-sum Tb rows (uint4 of 8 bf16 per lane), scale by 1/cnt,
//          add root+bias, ReLU, write node_out. No ballots/shfl tails.
__global__ __launch_bounds__(256)
void sort_aggregate(const int* __restrict__ x,
                    const int* __restrict__ obh,
                    const unsigned* __restrict__ rec,
                    const ushort_t* __restrict__ Tb,
                    const float* __restrict__ bias,
                    float* __restrict__ node_out) {
    __shared__ int cstart[257];
    __shared__ int cur[256];
    __shared__ int wsum4[4];
    __shared__ ushort_t sortedv[CAP];
    int b = blockIdx.x, t = threadIdx.x;
    int s = obh[b * SB];
    int e = (b + 1 < NB) ? obh[(b + 1) * SB] : N_EDGES;
    int ne = e - s;

    cstart[t] = 0;
    __syncthreads();
    // phase 1a: count keys (key = (nlow<<2)|r = low 8 payload bits)
    for (int i = t; i < ne; i += 256)
        atomicAdd(&cstart[rec[s + i] & 0xFFu], 1);
    __syncthreads();
    // phase 1b: 256-wide exclusive scan (4 waves + tiny top level)
    {
        int l = t & 63, wv = t >> 6;
        int v = cstart[t];
        int sc = v;
#pragma unroll
        for (int d = 1; d < 64; d <<= 1) {
            int tt = __shfl_up(sc, d, 64);
            if (l >= d) sc += tt;
        }
        if (l == 63) wsum4[wv] = sc;
        __syncthreads();
        if (t == 0) {
            int a = 0;
#pragma unroll
            for (int k = 0; k < 4; ++k) { int tmp = wsum4[k]; wsum4[k] = a; a += tmp; }
        }
        __syncthreads();
        int excl = sc - v + wsum4[wv];
        __syncthreads();            // cstart reads done above; safe to overwrite
        cstart[t] = excl;
        cur[t] = excl;
        if (t == 255) cstart[256] = excl + v;
    }
    __syncthreads();
    // phase 1c: place v values in (node,rel) order
    for (int i = t; i < ne; i += 256) {
        unsigned p = rec[s + i];
        int rk = atomicAdd(&cur[p & 0xFFu], 1);
        sortedv[rk] = (ushort_t)(p >> 8);
    }
    __syncthreads();

    // phase 2: gather-aggregate. group = t>>3 (0..31), sl = t&7.
    int grp = t >> 3;
    int sl  = t & 7;
#pragma unroll
    for (int nn = 0; nn < 2; ++nn) {
        int n = grp * 2 + nn;
        int node = b * NPB + n;
        if (node >= N_NODES) continue;
        float a0 = 0.f, a1 = 0.f, a2 = 0.f, a3 = 0.f,
              a4 = 0.f, a5 = 0.f, a6 = 0.f, a7 = 0.f;
#pragma unroll
        for (int r = 0; r < 3; ++r) {
            int k  = (n << 2) | r;
            int s0 = cstart[k];
            int c  = cstart[k + 1] - s0;
            const ushort_t* tbase = Tb + (size_t)(1 + r) * VOCAB * DIM + sl * 8;
            float g0 = 0.f, g1 = 0.f, g2 = 0.f, g3 = 0.f,
                  g4 = 0.f, g5 = 0.f, g6 = 0.f, g7 = 0.f;
            for (int i = s0; i < s0 + c; ++i) {
                unsigned vv = sortedv[i];           // 8 lanes same addr: broadcast
                const uint4 tv = *(const uint4*)(tbase + (size_t)vv * DIM);
                g0 += BFLO(tv.x); g1 += BFHI(tv.x);
                g2 += BFLO(tv.y); g3 += BFHI(tv.y);
                g4 += BFLO(tv.z); g5 += BFHI(tv.z);
                g6 += BFLO(tv.w); g7 += BFHI(tv.w);
            }
            float iv = 1.f / fmaxf((float)c, 1.f);
            a0 += g0 * iv; a1 += g1 * iv; a2 += g2 * iv; a3 += g3 * iv;
            a4 += g4 * iv; a5 += g5 * iv; a6 += g6 * iv; a7 += g7 * iv;
        }
        // root + bias + ReLU + store
        int xv = x[node];
        const uint4 rt = *(const uint4*)(Tb + (size_t)xv * DIM + sl * 8);
        const float4 b0 = *(const float4*)(bias + sl * 8);
        const float4 b1 = *(const float4*)(bias + sl * 8 + 4);
        float4 o0, o1;
        o0.x = fmaxf(BFLO(rt.x) + b0.x + a0, 0.f);
        o0.y = fmaxf(BFHI(rt.x) + b0.y + a1, 0.f);
        o0.z = fmaxf(BFLO(rt.y) + b0.z + a2, 0.f);
        o0.w = fmaxf(BFHI(rt.y) + b0.w + a3, 0.f);
        o1.x = fmaxf(BFLO(rt.z) + b1.x + a4, 0.f);
        o1.y = fmaxf(BFHI(rt.z) + b1.y + a5, 0.f);
        o1.z = fmaxf(BFLO(rt.w) + b1.z + a6, 0.f);
        o1.w = fmaxf(BFHI(rt.w) + b1.w + a7, 0.f);
        float* dstp = node_out + (size_t)node * DIM + sl * 8;
        *(float4*)(dstp)     = o0;
        *(float4*)(dstp + 4) = o1;
    }
}

// ---------------------------------------------------------------------------
// Kernel 6: per-graph mean pool + 64->2 linear. batch is SORTED. 8 waves/blk.
__device__ __forceinline__ int lbound(const int* __restrict__ b, int val) {
    int lo = 0, hi = N_NODES;
    while (lo < hi) {
        int mid = (lo + hi) >> 1;
        if (b[mid] < val) lo = mid + 1; else hi = mid;
    }
    return lo;
}

__global__ __launch_bounds__(512)
void pool_linear(const int* __restrict__ batch,
                 const float* __restrict__ node_out,
                 const float* __restrict__ lin_W,
                 const float* __restrict__ lin_b,
                 float* __restrict__ out) {
    __shared__ float sh[512];
    int g = blockIdx.x;
    int lane = threadIdx.x & 63;
    int w = threadIdx.x >> 6;      // 0..7
    int s = lbound(batch, g);
    int e = lbound(batch, g + 1);
    float acc = 0.f;
    for (int i = s + w; i < e; i += 8)
        acc += node_out[(size_t)i * DIM + lane];
    sh[threadIdx.x] = acc;
    __syncthreads();
    if (w == 0) {
        float tot = 0.f;
#pragma unroll
        for (int k = 0; k < 8; ++k) tot += sh[k * 64 + lane];
        float cnt = (float)(e - s);
        float mean = (e > s) ? tot / cnt : 0.f;
        float p0 = mean * lin_W[lane * 2 + 0];
        float p1 = mean * lin_W[lane * 2 + 1];
#pragma unroll
        for (int off2 = 32; off2 > 0; off2 >>= 1) {
            p0 += __shfl_down(p0, off2, 64);
            p1 += __shfl_down(p1, off2, 64);
        }
        if (lane == 0) {
            out[g * 2 + 0] = p0 + lin_b[0];
            out[g * 2 + 1] = p1 + lin_b[1];
        }
    }
}

// ---------------------------------------------------------------------------
extern "C" void kernel_launch(void* const* d_in, const int* in_sizes, int n_in,
                              void* d_out, int out_size, void* d_ws, size_t ws_size,
                              hipStream_t stream) {
    const int*   x      = (const int*)d_in[0];
    const int*   eidx   = (const int*)d_in[1];   // [2, E]
    const int*   etype  = (const int*)d_in[2];
    const int*   batch  = (const int*)d_in[3];
    const float* embed  = (const float*)d_in[4];
    const float* W_rel  = (const float*)d_in[5];
    const float* W_root = (const float*)d_in[6];
    const float* bias   = (const float*)d_in[7];
    const float* lin_W  = (const float*)d_in[8];
    const float* lin_b  = (const float*)d_in[9];
    float* out = (float*)d_out;

    const int* src = eidx;
    const int* dst = eidx + N_EDGES;

    // Workspace layout (bytes). No memsets; no aliasing (rec live during
    // node_out writes now).
    //   Tb       : 4*VOCAB*64*2  =  5,120,000   at          0
    //   rec      : 1M*4          =  4,000,000   at  5,120,000
    //   obh      : NELEMS*4      =  1,531,740   at  9,120,000
    //   bsum     : NSCAN*4       =      1,496   at 10,651,776
    //   bh       : NELEMS*4      =  1,531,740   at 10,653,312
    //   node_out : N*64*4        = 25,600,000   at 12,185,088 (16B aligned)
    //   total ≈ 37.8 MB
    char* ws = (char*)d_ws;
    ushort_t* Tb    = (ushort_t*)(ws);
    unsigned* rec   = (unsigned*)(ws + 5120000);
    int* obh        = (int*)(ws + 9120000);
    int* bsum       = (int*)(ws + 10651776);
    int* bh         = (int*)(ws + 10653312);
    float* node_out = (float*)(ws + 12185088);

    // 1. per-block bucket histogram (LDS atomics)
    bucket_hist<<<SB, 256, 0, stream>>>(dst, bh);

    // 2. bf16 transformed tables (independent; needed by sort_aggregate)
    build_tables<<<(4 * VOCAB) / 16, 256, 0, stream>>>(embed, W_rel, W_root, Tb);

    // 3. exclusive scan of (bucket,block) counts
    scan_block<<<NSCAN, SCAN_B, 0, stream>>>(bh, obh, bsum);
    scan_add<<<NSCAN, SCAN_B, 0, stream>>>(obh, bsum);

    // 4. bucket scatter (LDS ranks, no device atomics)
    bucket_scatter<<<SB, 256, 0, stream>>>(src, dst, etype, x, obh, rec);

    // 5. fused LDS node-sort + aggregation (no device atomics)
    sort_aggregate<<<NB, 256, 0, stream>>>(x, obh, rec, Tb, bias, node_out);

    // 6. per-graph pool + linear
    pool_linear<<<N_GRAPHS, 512, 0, stream>>>(batch, node_out, lin_W, lin_b, out);
}

// Round 10
// 99.080 us; speedup vs baseline: 4.6835x; 1.0486x over previous
//
#include <hip/hip_runtime.h>

#define N_NODES 100000
#define N_EDGES 1000000
#define N_GRAPHS 512
#define VOCAB 10000
#define DIM 64

#define NPB 64                                // nodes per bucket (dst>>6)
#define NB 1563                               // ceil(N_NODES/NPB)
#define EPB 4096                              // edges per hist/scatter block
#define SB 245                                // ceil(N_EDGES/EPB)
#define NELEMS (NB * SB)                      // 382,935 (bucket,block) counters
#define SCAN_B 1024
#define NSCAN ((NELEMS + SCAN_B - 1) / SCAN_B)  // 374
#define CAP 1152                              // LDS sorted-list capacity (mean 640, sigma 25)

typedef unsigned short ushort_t;

// f32 -> bf16 round-to-nearest-even
static __device__ __forceinline__ ushort_t f2bf(float f) {
    unsigned u = __float_as_uint(f);
    unsigned r = 0x7FFFu + ((u >> 16) & 1u);
    return (ushort_t)((u + r) >> 16);
}
#define BFLO(u) __uint_as_float((u) << 16)
#define BFHI(u) __uint_as_float((u) & 0xFFFF0000u)

// ---------------------------------------------------------------------------
// Kernel 1: bf16 transformed tables Tb[m][v][j] = (embed @ W_m), m=0 root.
__global__ void build_tables(const float* __restrict__ embed,
                             const float* __restrict__ W_rel,
                             const float* __restrict__ W_root,
                             ushort_t* __restrict__ Tb) {
    int tid  = blockIdx.x * 256 + threadIdx.x;
    int l    = tid & 63;
    int wave = tid >> 6;              // 0..9999
    int sub  = l >> 4;                // row-within-wave 0..3
    int q    = l & 15;                // feature quad
    int row  = wave * 4 + sub;        // wave never crosses m (10000%4==0)
    int m    = row / VOCAB;
    int v    = row - m * VOCAB;
    const float* W = (m == 0) ? W_root : (W_rel + (size_t)(m - 1) * DIM * DIM);
    float4 e4  = *(const float4*)(embed + (size_t)v * DIM + q * 4);
    float4 acc = {0.f, 0.f, 0.f, 0.f};
#pragma unroll
    for (int kk = 0; kk < 16; ++kk) {
        int srcl = sub * 16 + kk;
        float ex = __shfl(e4.x, srcl, 64);
        float ey = __shfl(e4.y, srcl, 64);
        float ez = __shfl(e4.z, srcl, 64);
        float ew = __shfl(e4.w, srcl, 64);
        const float4 w0 = *(const float4*)(W + (4 * kk + 0) * DIM + q * 4);
        const float4 w1 = *(const float4*)(W + (4 * kk + 1) * DIM + q * 4);
        const float4 w2 = *(const float4*)(W + (4 * kk + 2) * DIM + q * 4);
        const float4 w3 = *(const float4*)(W + (4 * kk + 3) * DIM + q * 4);
        acc.x += ex * w0.x; acc.y += ex * w0.y; acc.z += ex * w0.z; acc.w += ex * w0.w;
        acc.x += ey * w1.x; acc.y += ey * w1.y; acc.z += ey * w1.z; acc.w += ey * w1.w;
        acc.x += ez * w2.x; acc.y += ez * w2.y; acc.z += ez * w2.z; acc.w += ez * w2.w;
        acc.x += ew * w3.x; acc.y += ew * w3.y; acc.z += ew * w3.z; acc.w += ew * w3.w;
    }
    ushort_t* p = Tb + (size_t)row * DIM + q * 4;
    p[0] = f2bf(acc.x); p[1] = f2bf(acc.y);
    p[2] = f2bf(acc.z); p[3] = f2bf(acc.w);
}

// ---------------------------------------------------------------------------
// Kernel 2: per-block bucket histogram (LDS int atomics) + zero g_sum.
__global__ __launch_bounds__(256)
void bucket_hist(const int* __restrict__ dst, int* __restrict__ bh,
                 float* __restrict__ g_sum) {
    // zero g_sum (grid-stride; SB*256 = 62720 >= 32768 -> 1 store/thread max)
    for (int i = blockIdx.x * 256 + threadIdx.x; i < N_GRAPHS * DIM; i += SB * 256)
        g_sum[i] = 0.f;
    __shared__ int h[NB];
    for (int i = threadIdx.x; i < NB; i += 256) h[i] = 0;
    __syncthreads();
    int base = blockIdx.x * EPB;
    int lim  = base + EPB; if (lim > N_EDGES) lim = N_EDGES;
    for (int e = base + threadIdx.x; e < lim; e += 256)
        atomicAdd(&h[dst[e] >> 6], 1);               // LDS atomic
    __syncthreads();
    for (int i = threadIdx.x; i < NB; i += 256)
        bh[i * SB + blockIdx.x] = h[i];              // bucket-major
}

// ---------------------------------------------------------------------------
// Kernel 3a: per-1024-block exclusive scan (shfl-based).
__global__ __launch_bounds__(SCAN_B)
void scan_block(const int* __restrict__ bh, int* __restrict__ obh,
                int* __restrict__ bsum) {
    __shared__ int wsum[16];
    int i  = blockIdx.x * SCAN_B + threadIdx.x;
    int l  = threadIdx.x & 63;
    int wv = threadIdx.x >> 6;
    int v  = (i < NELEMS) ? bh[i] : 0;
    int s  = v;
#pragma unroll
    for (int d = 1; d < 64; d <<= 1) {
        int t = __shfl_up(s, d, 64);
        if (l >= d) s += t;
    }
    if (l == 63) wsum[wv] = s;
    __syncthreads();
    if (wv == 0) {
        int wval = (l < 16) ? wsum[l] : 0;
        int ss = wval;
#pragma unroll
        for (int d = 1; d < 16; d <<= 1) {
            int t = __shfl_up(ss, d, 64);
            if (l >= d) ss += t;
        }
        if (l == 15) bsum[blockIdx.x] = ss;
        if (l < 16)  wsum[l] = ss - wval;
    }
    __syncthreads();
    if (i < NELEMS) obh[i] = s - v + wsum[wv];
}

// Kernel 3b: add global block base (lane-strided partial sums of bsum).
__global__ __launch_bounds__(SCAN_B)
void scan_add(int* __restrict__ obh, const int* __restrict__ bsum) {
    __shared__ int base_sh;
    int blk = blockIdx.x;
    if (threadIdx.x < 64) {
        int l = threadIdx.x;
        int t = 0;
        for (int i = l; i < blk; i += 64) t += bsum[i];
#pragma unroll
        for (int d = 32; d > 0; d >>= 1) t += __shfl_xor(t, d, 64);
        if (l == 0) base_sh = t;
    }
    __syncthreads();
    int i = blk * SCAN_B + threadIdx.x;
    if (i < NELEMS) obh[i] += base_sh;
}

// ---------------------------------------------------------------------------
// Kernel 4: bucket scatter. Local rank via returning LDS atomic; global
// position = obh[bucket*SB + block] + rank. Record = (x[src]<<8|nlow<<2|rel).
__global__ __launch_bounds__(256)
void bucket_scatter(const int* __restrict__ src,
                    const int* __restrict__ dst,
                    const int* __restrict__ etype,
                    const int* __restrict__ x,
                    const int* __restrict__ obh,
                    unsigned* __restrict__ rec) {
    __shared__ int baseh[NB];
    __shared__ int h[NB];
    for (int i = threadIdx.x; i < NB; i += 256) {
        baseh[i] = obh[i * SB + blockIdx.x];
        h[i] = 0;
    }
    __syncthreads();
    int base = blockIdx.x * EPB;
    int lim  = base + EPB; if (lim > N_EDGES) lim = N_EDGES;
    for (int e = base + threadIdx.x; e < lim; e += 256) {
        int d = dst[e];
        int b = d >> 6;
        int rk = atomicAdd(&h[b], 1);                // LDS returning atomic (fast)
        unsigned payload = ((unsigned)x[src[e]] << 8)
                         | ((unsigned)(d & 63) << 2)
                         | (unsigned)etype[e];
        rec[baseh[b] + rk] = payload;
    }
}

// ---------------------------------------------------------------------------
// Kernel 5 (fused node_sort + aggregate + pool): block per bucket.
// Phase 1: LDS counting-sort of edges by (node,rel).
// Phase 2: 32 groups x 8 lanes gather-sum Tb rows -> node rows in LDS.
// Phase 3: per-graph tree-reduce of node rows (batch sorted => <=2-3 graphs
//          per bucket), one device f32 atomicAdd per (graph,feat).
__global__ __launch_bounds__(256)
void sort_aggregate(const int* __restrict__ x,
                    const int* __restrict__ batch,
                    const int* __restrict__ obh,
                    const unsigned* __restrict__ rec,
                    const ushort_t* __restrict__ Tb,
                    const float* __restrict__ bias,
                    float* __restrict__ g_sum) {
    __shared__ int cstart[257];
    __shared__ int cur[256];
    __shared__ int wsum4[4];
    __shared__ ushort_t sortedv[CAP];
    __shared__ float rows[NPB * DIM];     // 16 KB node-output rows
    __shared__ float red[256];
    __shared__ int batch_sh[NPB];
    int b = blockIdx.x, t = threadIdx.x;
    int s = obh[b * SB];
    int e = (b + 1 < NB) ? obh[(b + 1) * SB] : N_EDGES;
    int ne = e - s;
    int nvalid = N_NODES - b * NPB; if (nvalid > NPB) nvalid = NPB;

    cstart[t] = 0;
    if (t < NPB) batch_sh[t] = (t < nvalid) ? batch[b * NPB + t] : -1;
    __syncthreads();
    // phase 1a: count keys (key = (nlow<<2)|r = low 8 payload bits)
    for (int i = t; i < ne; i += 256)
        atomicAdd(&cstart[rec[s + i] & 0xFFu], 1);
    __syncthreads();
    // phase 1b: 256-wide exclusive scan (4 waves + tiny top level)
    {
        int l = t & 63, wv = t >> 6;
        int v = cstart[t];
        int sc = v;
#pragma unroll
        for (int d = 1; d < 64; d <<= 1) {
            int tt = __shfl_up(sc, d, 64);
            if (l >= d) sc += tt;
        }
        if (l == 63) wsum4[wv] = sc;
        __syncthreads();
        if (t == 0) {
            int a = 0;
#pragma unroll
            for (int k = 0; k < 4; ++k) { int tmp = wsum4[k]; wsum4[k] = a; a += tmp; }
        }
        __syncthreads();
        int excl = sc - v + wsum4[wv];
        __syncthreads();            // cstart reads done above; safe to overwrite
        cstart[t] = excl;
        cur[t] = excl;
        if (t == 255) cstart[256] = excl + v;
    }
    __syncthreads();
    // phase 1c: place v values in (node,rel) order
    for (int i = t; i < ne; i += 256) {
        unsigned p = rec[s + i];
        int rk = atomicAdd(&cur[p & 0xFFu], 1);
        sortedv[rk] = (ushort_t)(p >> 8);
    }
    __syncthreads();

    // phase 2: gather-aggregate. group = t>>3 (0..31), sl = t&7.
    int grp = t >> 3;
    int sl  = t & 7;
#pragma unroll
    for (int nn = 0; nn < 2; ++nn) {
        int n = grp * 2 + nn;
        if (n >= nvalid) continue;
        int node = b * NPB + n;
        float a0 = 0.f, a1 = 0.f, a2 = 0.f, a3 = 0.f,
              a4 = 0.f, a5 = 0.f, a6 = 0.f, a7 = 0.f;
#pragma unroll
        for (int r = 0; r < 3; ++r) {
            int k  = (n << 2) | r;
            int s0 = cstart[k];
            int c  = cstart[k + 1] - s0;
            const ushort_t* tbase = Tb + (size_t)(1 + r) * VOCAB * DIM + sl * 8;
            float g0 = 0.f, g1 = 0.f, g2 = 0.f, g3 = 0.f,
                  g4 = 0.f, g5 = 0.f, g6 = 0.f, g7 = 0.f;
            for (int i = s0; i < s0 + c; ++i) {
                unsigned vv = sortedv[i];           // 8 lanes same addr: broadcast
                const uint4 tv = *(const uint4*)(tbase + (size_t)vv * DIM);
                g0 += BFLO(tv.x); g1 += BFHI(tv.x);
                g2 += BFLO(tv.y); g3 += BFHI(tv.y);
                g4 += BFLO(tv.z); g5 += BFHI(tv.z);
                g6 += BFLO(tv.w); g7 += BFHI(tv.w);
            }
            float iv = 1.f / fmaxf((float)c, 1.f);
            a0 += g0 * iv; a1 += g1 * iv; a2 += g2 * iv; a3 += g3 * iv;
            a4 += g4 * iv; a5 += g5 * iv; a6 += g6 * iv; a7 += g7 * iv;
        }
        // root + bias + ReLU -> LDS rows
        int xv = x[node];
        const uint4 rt = *(const uint4*)(Tb + (size_t)xv * DIM + sl * 8);
        const float4 b0 = *(const float4*)(bias + sl * 8);
        const float4 b1 = *(const float4*)(bias + sl * 8 + 4);
        float* rp = rows + n * DIM + sl * 8;
        rp[0] = fmaxf(BFLO(rt.x) + b0.x + a0, 0.f);
        rp[1] = fmaxf(BFHI(rt.x) + b0.y + a1, 0.f);
        rp[2] = fmaxf(BFLO(rt.y) + b0.z + a2, 0.f);
        rp[3] = fmaxf(BFHI(rt.y) + b0.w + a3, 0.f);
        rp[4] = fmaxf(BFLO(rt.z) + b1.x + a4, 0.f);
        rp[5] = fmaxf(BFHI(rt.z) + b1.y + a5, 0.f);
        rp[6] = fmaxf(BFLO(rt.w) + b1.z + a6, 0.f);
        rp[7] = fmaxf(BFHI(rt.w) + b1.w + a7, 0.f);
    }
    __syncthreads();

    // phase 3: per-graph pooling reduce (batch sorted: few graphs/bucket).
    int gmin = batch_sh[0];
    int gmax = batch_sh[nvalid - 1];
    int f  = t & 63;                    // feature
    int n0 = t >> 6;                    // 4-thread stride over nodes
    for (int g = gmin; g <= gmax; ++g) {
        float a = 0.f;
        for (int n = n0; n < nvalid; n += 4)
            a += (batch_sh[n] == g) ? rows[n * DIM + f] : 0.f;
        red[t] = a;
        __syncthreads();
        if (t < 64) {
            float tot = red[t] + red[t + 64] + red[t + 128] + red[t + 192];
            if (tot != 0.f) atomicAdd(&g_sum[g * DIM + t], tot);
        }
        __syncthreads();
    }
}

// ---------------------------------------------------------------------------
// Kernel 6: per-graph mean + 64->2 linear. 512 blocks x 64 lanes.
__device__ __forceinline__ int lbound(const int* __restrict__ b, int val) {
    int lo = 0, hi = N_NODES;
    while (lo < hi) {
        int mid = (lo + hi) >> 1;
        if (b[mid] < val) lo = mid + 1; else hi = mid;
    }
    return lo;
}

__global__ __launch_bounds__(64)
void final_linear(const int* __restrict__ batch,
                  const float* __restrict__ g_sum,
                  const float* __restrict__ lin_W,
                  const float* __restrict__ lin_b,
                  float* __restrict__ out) {
    int g = blockIdx.x;
    int l = threadIdx.x;   // 0..63
    int s = lbound(batch, g);
    int e = lbound(batch, g + 1);
    float mean = (e > s) ? g_sum[g * DIM + l] / (float)(e - s) : 0.f;
    float p0 = mean * lin_W[l * 2 + 0];
    float p1 = mean * lin_W[l * 2 + 1];
#pragma unroll
    for (int off2 = 32; off2 > 0; off2 >>= 1) {
        p0 += __shfl_down(p0, off2, 64);
        p1 += __shfl_down(p1, off2, 64);
    }
    if (l == 0) {
        out[g * 2 + 0] = p0 + lin_b[0];
        out[g * 2 + 1] = p1 + lin_b[1];
    }
}

// ---------------------------------------------------------------------------
extern "C" void kernel_launch(void* const* d_in, const int* in_sizes, int n_in,
                              void* d_out, int out_size, void* d_ws, size_t ws_size,
                              hipStream_t stream) {
    const int*   x      = (const int*)d_in[0];
    const int*   eidx   = (const int*)d_in[1];   // [2, E]
    const int*   etype  = (const int*)d_in[2];
    const int*   batch  = (const int*)d_in[3];
    const float* embed  = (const float*)d_in[4];
    const float* W_rel  = (const float*)d_in[5];
    const float* W_root = (const float*)d_in[6];
    const float* bias   = (const float*)d_in[7];
    const float* lin_W  = (const float*)d_in[8];
    const float* lin_b  = (const float*)d_in[9];
    float* out = (float*)d_out;

    const int* src = eidx;
    const int* dst = eidx + N_EDGES;

    // Workspace layout (bytes). No memsets (g_sum zeroed in bucket_hist).
    //   Tb    : 4*VOCAB*64*2  = 5,120,000   at          0
    //   rec   : 1M*4          = 4,000,000   at  5,120,000
    //   obh   : NELEMS*4      = 1,531,740   at  9,120,000
    //   bsum  : NSCAN*4       =     1,496   at 10,651,776
    //   bh    : NELEMS*4      = 1,531,740   at 10,653,312
    //   g_sum : 512*64*4      =   131,072   at 12,185,088
    //   total ~ 12.3 MB
    char* ws = (char*)d_ws;
    ushort_t* Tb    = (ushort_t*)(ws);
    unsigned* rec   = (unsigned*)(ws + 5120000);
    int* obh        = (int*)(ws + 9120000);
    int* bsum       = (int*)(ws + 10651776);
    int* bh         = (int*)(ws + 10653312);
    float* g_sum    = (float*)(ws + 12185088);

    // 1. per-block bucket histogram (LDS atomics) + zero g_sum
    bucket_hist<<<SB, 256, 0, stream>>>(dst, bh, g_sum);

    // 2. bf16 transformed tables (independent; needed by sort_aggregate)
    build_tables<<<(4 * VOCAB) / 16, 256, 0, stream>>>(embed, W_rel, W_root, Tb);

    // 3. exclusive scan of (bucket,block) counts
    scan_block<<<NSCAN, SCAN_B, 0, stream>>>(bh, obh, bsum);
    scan_add<<<NSCAN, SCAN_B, 0, stream>>>(obh, bsum);

    // 4. bucket scatter (LDS ranks, no device atomics)
    bucket_scatter<<<SB, 256, 0, stream>>>(src, dst, etype, x, obh, rec);

    // 5. fused LDS node-sort + aggregation + pooling
    sort_aggregate<<<NB, 256, 0, stream>>>(x, batch, obh, rec, Tb, bias, g_sum);

    // 6. per-graph mean + linear
    final_linear<<<N_GRAPHS, 64, 0, stream>>>(batch, g_sum, lin_W, lin_b, out);
}

// Round 11
// 87.460 us; speedup vs baseline: 5.3058x; 1.1329x over previous
//
#include <hip/hip_runtime.h>

#define N_NODES 100000
#define N_EDGES 1000000
#define N_GRAPHS 512
#define VOCAB 10000
#define DIM 64

#define NPB 64                                // nodes per bucket (dst>>6)
#define NB 1563                               // ceil(N_NODES/NPB)
#define EPB 4096                              // edges per hist/scatter block
#define SB 245                                // ceil(N_EDGES/EPB)
#define NELEMS (NB * SB)                      // 382,935 (bucket,block) counters
#define BUILD_BLOCKS ((4 * VOCAB) / 16)       // 2500
#define CAP 1152                              // LDS sorted-list capacity (mean 640)

typedef unsigned short ushort_t;

// f32 -> bf16 round-to-nearest-even
static __device__ __forceinline__ ushort_t f2bf(float f) {
    unsigned u = __float_as_uint(f);
    unsigned r = 0x7FFFu + ((u >> 16) & 1u);
    return (ushort_t)((u + r) >> 16);
}
#define BFLO(u) __uint_as_float((u) << 16)
#define BFHI(u) __uint_as_float((u) & 0xFFFF0000u)

// ---------------------------------------------------------------------------
// Kernel 1 (fused): blocks [0,SB) = bucket histogram (LDS atomics) + g_sum
// zero; blocks [SB, SB+BUILD_BLOCKS) = bf16 transformed tables.
__global__ __launch_bounds__(256)
void hist_build(const int* __restrict__ dst, int* __restrict__ bh,
                float* __restrict__ g_sum,
                const float* __restrict__ embed,
                const float* __restrict__ W_rel,
                const float* __restrict__ W_root,
                ushort_t* __restrict__ Tb) {
    if (blockIdx.x < SB) {
        // --- bucket histogram ---
        for (int i = blockIdx.x * 256 + threadIdx.x; i < N_GRAPHS * DIM; i += SB * 256)
            g_sum[i] = 0.f;
        __shared__ int h[NB];
        for (int i = threadIdx.x; i < NB; i += 256) h[i] = 0;
        __syncthreads();
        int base = blockIdx.x * EPB;
        int lim  = base + EPB; if (lim > N_EDGES) lim = N_EDGES;
        for (int e = base + threadIdx.x; e < lim; e += 256)
            atomicAdd(&h[dst[e] >> 6], 1);               // LDS atomic
        __syncthreads();
        for (int i = threadIdx.x; i < NB; i += 256)
            bh[i * SB + blockIdx.x] = h[i];              // bucket-major
    } else {
        // --- build tables: 4 rows per wave; float4 math, bf16 store ---
        int tid  = (blockIdx.x - SB) * 256 + threadIdx.x;
        int l    = tid & 63;
        int wave = tid >> 6;              // 0..9999
        int sub  = l >> 4;                // row-within-wave 0..3
        int q    = l & 15;                // feature quad
        int row  = wave * 4 + sub;        // wave never crosses m (10000%4==0)
        int m    = row / VOCAB;
        int v    = row - m * VOCAB;
        const float* W = (m == 0) ? W_root : (W_rel + (size_t)(m - 1) * DIM * DIM);
        float4 e4  = *(const float4*)(embed + (size_t)v * DIM + q * 4);
        float4 acc = {0.f, 0.f, 0.f, 0.f};
#pragma unroll
        for (int kk = 0; kk < 16; ++kk) {
            int srcl = sub * 16 + kk;
            float ex = __shfl(e4.x, srcl, 64);
            float ey = __shfl(e4.y, srcl, 64);
            float ez = __shfl(e4.z, srcl, 64);
            float ew = __shfl(e4.w, srcl, 64);
            const float4 w0 = *(const float4*)(W + (4 * kk + 0) * DIM + q * 4);
            const float4 w1 = *(const float4*)(W + (4 * kk + 1) * DIM + q * 4);
            const float4 w2 = *(const float4*)(W + (4 * kk + 2) * DIM + q * 4);
            const float4 w3 = *(const float4*)(W + (4 * kk + 3) * DIM + q * 4);
            acc.x += ex * w0.x; acc.y += ex * w0.y; acc.z += ex * w0.z; acc.w += ex * w0.w;
            acc.x += ey * w1.x; acc.y += ey * w1.y; acc.z += ey * w1.z; acc.w += ey * w1.w;
            acc.x += ez * w2.x; acc.y += ez * w2.y; acc.z += ez * w2.z; acc.w += ez * w2.w;
            acc.x += ew * w3.x; acc.y += ew * w3.y; acc.z += ew * w3.z; acc.w += ew * w3.w;
        }
        ushort_t* p = Tb + (size_t)row * DIM + q * 4;
        p[0] = f2bf(acc.x); p[1] = f2bf(acc.y);
        p[2] = f2bf(acc.z); p[3] = f2bf(acc.w);
    }
}

// ---------------------------------------------------------------------------
// Kernel 2: per-bucket row scan. Block b: exclusive scan of bh[b][0..SB),
// writes block-local prefixes loc[] and bucket total btot[b].
__global__ __launch_bounds__(256)
void rowscan(const int* __restrict__ bh, int* __restrict__ loc,
             int* __restrict__ btot) {
    __shared__ int wsum4[4];
    int b = blockIdx.x, t = threadIdx.x;
    int l = t & 63, wv = t >> 6;
    int v = (t < SB) ? bh[b * SB + t] : 0;
    int sc = v;
#pragma unroll
    for (int d = 1; d < 64; d <<= 1) {
        int tt = __shfl_up(sc, d, 64);
        if (l >= d) sc += tt;
    }
    if (l == 63) wsum4[wv] = sc;
    __syncthreads();
    if (t == 0) {
        int a = 0;
#pragma unroll
        for (int k = 0; k < 4; ++k) { int tmp = wsum4[k]; wsum4[k] = a; a += tmp; }
    }
    __syncthreads();
    int excl = sc - v + wsum4[wv];
    if (t < SB) loc[b * SB + t] = excl;
    if (t == 255) btot[b] = excl;          // v==0 at t=255 -> excl == total
}

// ---------------------------------------------------------------------------
// Kernel 3: global scan of the 1563 bucket totals -> bbase[0..NB].
__global__ __launch_bounds__(1024)
void gscan(const int* __restrict__ btot, int* __restrict__ bbase) {
    __shared__ int wsum[16];
    int t = threadIdx.x;
    int i0 = 2 * t, i1 = 2 * t + 1;
    int a = (i0 < NB) ? btot[i0] : 0;
    int c = (i1 < NB) ? btot[i1] : 0;
    int pv = a + c;
    int l = t & 63, wv = t >> 6;
    int sc = pv;
#pragma unroll
    for (int d = 1; d < 64; d <<= 1) {
        int tt = __shfl_up(sc, d, 64);
        if (l >= d) sc += tt;
    }
    if (l == 63) wsum[wv] = sc;
    __syncthreads();
    if (wv == 0) {
        int wval = (l < 16) ? wsum[l] : 0;
        int ss = wval;
#pragma unroll
        for (int d = 1; d < 16; d <<= 1) {
            int tt = __shfl_up(ss, d, 64);
            if (l >= d) ss += tt;
        }
        if (l < 16) wsum[l] = ss - wval;
    }
    __syncthreads();
    int E = sc - pv + wsum[wv];
    if (i0 <= NB) bbase[i0] = E;
    if (i1 <= NB) bbase[i1] = E + a;
}

// ---------------------------------------------------------------------------
// Kernel 4: bucket scatter (512 threads). Local rank via returning LDS
// atomic; pos = bbase[b] + loc[b][blk] + rank. rec = (x[src]<<8|nlow<<2|rel).
__global__ __launch_bounds__(512)
void bucket_scatter(const int* __restrict__ src,
                    const int* __restrict__ dst,
                    const int* __restrict__ etype,
                    const int* __restrict__ x,
                    const int* __restrict__ loc,
                    const int* __restrict__ bbase,
                    unsigned* __restrict__ rec) {
    __shared__ int baseh[NB];
    __shared__ int h[NB];
    for (int i = threadIdx.x; i < NB; i += 512) {
        baseh[i] = bbase[i] + loc[i * SB + blockIdx.x];
        h[i] = 0;
    }
    __syncthreads();
    int base = blockIdx.x * EPB;
    int lim  = base + EPB; if (lim > N_EDGES) lim = N_EDGES;
    for (int e = base + threadIdx.x; e < lim; e += 512) {
        int d = dst[e];
        int b = d >> 6;
        int rk = atomicAdd(&h[b], 1);                // LDS returning atomic
        unsigned payload = ((unsigned)x[src[e]] << 8)
                         | ((unsigned)(d & 63) << 2)
                         | (unsigned)etype[e];
        rec[baseh[b] + rk] = payload;
    }
}

// ---------------------------------------------------------------------------
// Kernel 5 (fused sort + aggregate + pool): block per bucket.
// Phase 1: LDS counting-sort by key=(nlow<<2)|rel; per-key inv table.
// Phase 2: 32 groups x 8 lanes; flat per-node edge loop, 2-way unrolled
//          (two independent 16B gathers in flight), per-edge scale by inv.
// Phase 3: per-graph reduce of LDS rows -> device atomicAdd into g_sum.
__global__ __launch_bounds__(256)
void sort_aggregate(const int* __restrict__ x,
                    const int* __restrict__ batch,
                    const int* __restrict__ bbase,
                    const unsigned* __restrict__ rec,
                    const ushort_t* __restrict__ Tb,
                    const float* __restrict__ bias,
                    float* __restrict__ g_sum) {
    __shared__ int cstart[257];
    __shared__ int cur[256];
    __shared__ int wsum4[4];
    __shared__ float inv_sh[256];
    __shared__ unsigned sortedc[CAP];
    __shared__ float rows[NPB * DIM];     // 16 KB node-output rows
    __shared__ float red[256];
    __shared__ int batch_sh[NPB];
    int b = blockIdx.x, t = threadIdx.x;
    int s = bbase[b];
    int e = bbase[b + 1];
    int ne = e - s;
    int nvalid = N_NODES - b * NPB; if (nvalid > NPB) nvalid = NPB;

    cstart[t] = 0;
    if (t < NPB) batch_sh[t] = (t < nvalid) ? batch[b * NPB + t] : -1;
    __syncthreads();
    // phase 1a: count keys (key = low 8 payload bits)
    for (int i = t; i < ne; i += 256)
        atomicAdd(&cstart[rec[s + i] & 0xFFu], 1);
    __syncthreads();
    // phase 1b: 256-wide exclusive scan of counts
    {
        int l = t & 63, wv = t >> 6;
        int v = cstart[t];
        int sc = v;
#pragma unroll
        for (int d = 1; d < 64; d <<= 1) {
            int tt = __shfl_up(sc, d, 64);
            if (l >= d) sc += tt;
        }
        if (l == 63) wsum4[wv] = sc;
        __syncthreads();
        if (t == 0) {
            int a = 0;
#pragma unroll
            for (int k = 0; k < 4; ++k) { int tmp = wsum4[k]; wsum4[k] = a; a += tmp; }
        }
        __syncthreads();
        int excl = sc - v + wsum4[wv];
        __syncthreads();            // cstart reads done; safe to overwrite
        cstart[t] = excl;
        cur[t] = excl;
        if (t == 255) cstart[256] = excl + v;
    }
    __syncthreads();
    // per-key inverse counts
    inv_sh[t] = 1.f / fmaxf((float)(cstart[t + 1] - cstart[t]), 1.f);
    // phase 1c: place records in (node,rel) order (record IS the combo)
    for (int i = t; i < ne; i += 256) {
        unsigned p = rec[s + i];
        int rk = atomicAdd(&cur[p & 0xFFu], 1);
        sortedc[rk] = p;
    }
    __syncthreads();

    // phase 2: gather-aggregate. group = t>>3 (0..31), sl = t&7.
    int grp = t >> 3;
    int sl  = t & 7;
    const ushort_t* TbRel = Tb + (size_t)VOCAB * DIM;   // relation tables base
#pragma unroll
    for (int nn = 0; nn < 2; ++nn) {
        int n = grp * 2 + nn;
        if (n >= nvalid) continue;
        int node = b * NPB + n;
        int i0 = cstart[n << 2];
        int i1 = cstart[(n + 1) << 2];
        float a0 = 0.f, a1 = 0.f, a2 = 0.f, a3 = 0.f,
              a4 = 0.f, a5 = 0.f, a6 = 0.f, a7 = 0.f;
        int i = i0;
        for (; i + 2 <= i1; i += 2) {                  // 2 gathers in flight
            unsigned c1 = sortedc[i], c2 = sortedc[i + 1];
            const uint4 t1 = *(const uint4*)(TbRel +
                ((size_t)(c1 & 3u) * VOCAB + (c1 >> 8)) * DIM + sl * 8);
            const uint4 t2 = *(const uint4*)(TbRel +
                ((size_t)(c2 & 3u) * VOCAB + (c2 >> 8)) * DIM + sl * 8);
            float iv1 = inv_sh[c1 & 0xFFu];
            float iv2 = inv_sh[c2 & 0xFFu];
            a0 += BFLO(t1.x) * iv1; a1 += BFHI(t1.x) * iv1;
            a2 += BFLO(t1.y) * iv1; a3 += BFHI(t1.y) * iv1;
            a4 += BFLO(t1.z) * iv1; a5 += BFHI(t1.z) * iv1;
            a6 += BFLO(t1.w) * iv1; a7 += BFHI(t1.w) * iv1;
            a0 += BFLO(t2.x) * iv2; a1 += BFHI(t2.x) * iv2;
            a2 += BFLO(t2.y) * iv2; a3 += BFHI(t2.y) * iv2;
            a4 += BFLO(t2.z) * iv2; a5 += BFHI(t2.z) * iv2;
            a6 += BFLO(t2.w) * iv2; a7 += BFHI(t2.w) * iv2;
        }
        if (i < i1) {                                   // tail edge
            unsigned c1 = sortedc[i];
            const uint4 t1 = *(const uint4*)(TbRel +
                ((size_t)(c1 & 3u) * VOCAB + (c1 >> 8)) * DIM + sl * 8);
            float iv1 = inv_sh[c1 & 0xFFu];
            a0 += BFLO(t1.x) * iv1; a1 += BFHI(t1.x) * iv1;
            a2 += BFLO(t1.y) * iv1; a3 += BFHI(t1.y) * iv1;
            a4 += BFLO(t1.z) * iv1; a5 += BFHI(t1.z) * iv1;
            a6 += BFLO(t1.w) * iv1; a7 += BFHI(t1.w) * iv1;
        }
        // root + bias + ReLU -> LDS rows
        int xv = x[node];
        const uint4 rt = *(const uint4*)(Tb + (size_t)xv * DIM + sl * 8);
        const float4 b0 = *(const float4*)(bias + sl * 8);
        const float4 b1 = *(const float4*)(bias + sl * 8 + 4);
        float* rp = rows + n * DIM + sl * 8;
        rp[0] = fmaxf(BFLO(rt.x) + b0.x + a0, 0.f);
        rp[1] = fmaxf(BFHI(rt.x) + b0.y + a1, 0.f);
        rp[2] = fmaxf(BFLO(rt.y) + b0.z + a2, 0.f);
        rp[3] = fmaxf(BFHI(rt.y) + b0.w + a3, 0.f);
        rp[4] = fmaxf(BFLO(rt.z) + b1.x + a4, 0.f);
        rp[5] = fmaxf(BFHI(rt.z) + b1.y + a5, 0.f);
        rp[6] = fmaxf(BFLO(rt.w) + b1.z + a6, 0.f);
        rp[7] = fmaxf(BFHI(rt.w) + b1.w + a7, 0.f);
    }
    __syncthreads();

    // phase 3: per-graph pooling reduce (batch sorted: few graphs/bucket).
    int gmin = batch_sh[0];
    int gmax = batch_sh[nvalid - 1];
    int f  = t & 63;                    // feature
    int n0 = t >> 6;                    // 4-thread stride over nodes
    for (int g = gmin; g <= gmax; ++g) {
        float a = 0.f;
        for (int n = n0; n < nvalid; n += 4)
            a += (batch_sh[n] == g) ? rows[n * DIM + f] : 0.f;
        red[t] = a;
        __syncthreads();
        if (t < 64) {
            float tot = red[t] + red[t + 64] + red[t + 128] + red[t + 192];
            if (tot != 0.f) atomicAdd(&g_sum[g * DIM + t], tot);
        }
        __syncthreads();
    }
}

// ---------------------------------------------------------------------------
// Kernel 6: per-graph mean + 64->2 linear. 512 blocks x 64 lanes.
__device__ __forceinline__ int lbound(const int* __restrict__ b, int val) {
    int lo = 0, hi = N_NODES;
    while (lo < hi) {
        int mid = (lo + hi) >> 1;
        if (b[mid] < val) lo = mid + 1; else hi = mid;
    }
    return lo;
}

__global__ __launch_bounds__(64)
void final_linear(const int* __restrict__ batch,
                  const float* __restrict__ g_sum,
                  const float* __restrict__ lin_W,
                  const float* __restrict__ lin_b,
                  float* __restrict__ out) {
    int g = blockIdx.x;
    int l = threadIdx.x;   // 0..63
    int s = lbound(batch, g);
    int e = lbound(batch, g + 1);
    float mean = (e > s) ? g_sum[g * DIM + l] / (float)(e - s) : 0.f;
    float p0 = mean * lin_W[l * 2 + 0];
    float p1 = mean * lin_W[l * 2 + 1];
#pragma unroll
    for (int off2 = 32; off2 > 0; off2 >>= 1) {
        p0 += __shfl_down(p0, off2, 64);
        p1 += __shfl_down(p1, off2, 64);
    }
    if (l == 0) {
        out[g * 2 + 0] = p0 + lin_b[0];
        out[g * 2 + 1] = p1 + lin_b[1];
    }
}

// ---------------------------------------------------------------------------
extern "C" void kernel_launch(void* const* d_in, const int* in_sizes, int n_in,
                              void* d_out, int out_size, void* d_ws, size_t ws_size,
                              hipStream_t stream) {
    const int*   x      = (const int*)d_in[0];
    const int*   eidx   = (const int*)d_in[1];   // [2, E]
    const int*   etype  = (const int*)d_in[2];
    const int*   batch  = (const int*)d_in[3];
    const float* embed  = (const float*)d_in[4];
    const float* W_rel  = (const float*)d_in[5];
    const float* W_root = (const float*)d_in[6];
    const float* bias   = (const float*)d_in[7];
    const float* lin_W  = (const float*)d_in[8];
    const float* lin_b  = (const float*)d_in[9];
    float* out = (float*)d_out;

    const int* src = eidx;
    const int* dst = eidx + N_EDGES;

    // Workspace layout (bytes). No memsets (g_sum zeroed in hist_build).
    //   Tb    : 4*VOCAB*64*2  = 5,120,000   at          0
    //   rec   : 1M*4          = 4,000,000   at  5,120,000
    //   loc   : NELEMS*4      = 1,531,740   at  9,120,000
    //   btot  : NB*4          =     6,252   at 10,651,776
    //   bbase : (NB+1)*4      =     6,256   at 10,658,048
    //   bh    : NELEMS*4      = 1,531,740   at 10,664,320
    //   g_sum : 512*64*4      =   131,072   at 12,196,096
    //   total ~ 12.33 MB
    char* ws = (char*)d_ws;
    ushort_t* Tb    = (ushort_t*)(ws);
    unsigned* rec   = (unsigned*)(ws + 5120000);
    int* loc        = (int*)(ws + 9120000);
    int* btot       = (int*)(ws + 10651776);
    int* bbase      = (int*)(ws + 10658048);
    int* bh         = (int*)(ws + 10664320);
    float* g_sum    = (float*)(ws + 12196096);

    // 1. fused: bucket histogram (+g_sum zero)  ||  bf16 table build
    hist_build<<<SB + BUILD_BLOCKS, 256, 0, stream>>>(
        dst, bh, g_sum, embed, W_rel, W_root, Tb);

    // 2. per-bucket row scan -> loc, btot
    rowscan<<<NB, 256, 0, stream>>>(bh, loc, btot);

    // 3. global scan of bucket totals -> bbase
    gscan<<<1, 1024, 0, stream>>>(btot, bbase);

    // 4. bucket scatter (LDS ranks, no device atomics)
    bucket_scatter<<<SB, 512, 0, stream>>>(src, dst, etype, x, loc, bbase, rec);

    // 5. fused LDS sort + aggregation + pooling
    sort_aggregate<<<NB, 256, 0, stream>>>(x, batch, bbase, rec, Tb, bias, g_sum);

    // 6. per-graph mean + linear
    final_linear<<<N_GRAPHS, 64, 0, stream>>>(batch, g_sum, lin_W, lin_b, out);
}